// Round 1
// 14509.720 us; speedup vs baseline: 1.4293x; 1.4293x over previous
//
#include <hip/hip_runtime.h>
#include <math.h>

#define D 768
#define T 1024
#define BATCH 2
#define NH 12
#define NL 12
#define V 50257
#define NT 2048  // BATCH*T

typedef _Float16 half4_t __attribute__((ext_vector_type(4)));
typedef _Float16 half8_t __attribute__((ext_vector_type(8)));
typedef float floatx4 __attribute__((ext_vector_type(4)));

// ---------------- wave helpers ----------------
__device__ inline float wave_reduce_sum(float v) {
  #pragma unroll
  for (int off = 32; off > 0; off >>= 1) v += __shfl_xor(v, off, 64);
  return v;
}
__device__ inline float wave_reduce_max(float v) {
  #pragma unroll
  for (int off = 32; off > 0; off >>= 1) v = fmaxf(v, __shfl_xor(v, off, 64));
  return v;
}

// ---------------- embedding ----------------
__global__ __launch_bounds__(256) void embed_kernel(const int* __restrict__ idx,
    const float* __restrict__ wte, const float* __restrict__ pos,
    float* __restrict__ x) {
  int row = blockIdx.x;                 // 0..NT-1
  int tok = idx[row];
  int tp  = row & (T - 1);
  const float* ws = wte + (size_t)tok * D;
  const float* ps = pos + (size_t)tp * D;
  float* xr = x + (size_t)row * D;
  for (int i = threadIdx.x; i < D; i += 256) xr[i] = ws[i] + ps[i];
}

// ---------------- layernorm ----------------
__global__ __launch_bounds__(256) void ln_kernel(const float* __restrict__ x,
    const float* __restrict__ g, const float* __restrict__ bta,
    float* __restrict__ y) {
  int row = blockIdx.x;
  const float* xr = x + (size_t)row * D;
  float* yr = y + (size_t)row * D;
  int t = threadIdx.x, lane = t & 63, wid = t >> 6;
  __shared__ float red[4];
  __shared__ float s_mean, s_rstd;

  float s = 0.f;
  for (int i = t; i < D; i += 256) s += xr[i];
  s = wave_reduce_sum(s);
  if (lane == 0) red[wid] = s;
  __syncthreads();
  if (t == 0) s_mean = (red[0] + red[1] + red[2] + red[3]) * (1.f / D);
  __syncthreads();
  float mean = s_mean;

  float v = 0.f;
  for (int i = t; i < D; i += 256) { float d = xr[i] - mean; v += d * d; }
  v = wave_reduce_sum(v);
  if (lane == 0) red[wid] = v;
  __syncthreads();
  if (t == 0) s_rstd = rsqrtf((red[0] + red[1] + red[2] + red[3]) * (1.f / D) + 1e-5f);
  __syncthreads();
  float rstd = s_rstd;

  for (int i = t; i < D; i += 256)
    yr[i] = (xr[i] - mean) * rstd * g[i] + bta[i];
}

// ---------------- attention (one wave per (b,h,q-row)) ----------------
__global__ __launch_bounds__(64) void attn_kernel(const float* __restrict__ qkv,
                                                  float* __restrict__ o) {
  const int tq   = blockIdx.x;
  const int h    = blockIdx.y;
  const int b    = blockIdx.z;
  const int lane = threadIdx.x;
  __shared__ float qs[64];
  __shared__ float s[T];
  const int RS = 3 * D;  // qkv row stride

  const float* qp = qkv + (size_t)(b * T + tq) * RS + h * 64;
  qs[lane] = qp[lane];
  __syncthreads();

  // scores (causal: keys 0..tq)
  for (int k = lane; k <= tq; k += 64) {
    const float* kp = qkv + (size_t)(b * T + k) * RS + D + h * 64;
    float acc = 0.f;
    #pragma unroll
    for (int d2 = 0; d2 < 64; ++d2) acc = fmaf(qs[d2], kp[d2], acc);
    s[k] = acc * 0.125f;  // 1/sqrt(64)
  }
  __syncthreads();

  float m = -1e30f;
  for (int k = lane; k <= tq; k += 64) m = fmaxf(m, s[k]);
  m = wave_reduce_max(m);
  float sum = 0.f;
  for (int k = lane; k <= tq; k += 64) { float p = expf(s[k] - m); s[k] = p; sum += p; }
  sum = wave_reduce_sum(sum);
  __syncthreads();
  float inv = 1.f / sum;

  // PV: lane owns output dim `lane`
  const float* vbase = qkv + (size_t)(b * T) * RS + 2 * D + h * 64 + lane;
  float acc = 0.f;
  for (int k = 0; k <= tq; ++k) acc = fmaf(s[k], vbase[(size_t)k * RS], acc);
  o[(size_t)(b * T + tq) * D + h * 64 + lane] = acc * inv;
}

// ---------------- fp16 MFMA tiled GEMM: C[M,N] = A[M,K] @ B (+epilogue) ----------
// Inputs are fp32 in HBM; converted to fp16 during LDS staging. fp32 accumulate.
// BT=false: B is [K,N] row-major. BT=true: B is [N,K] row-major (C = A @ B^T).
// bias (len N) and res (same shape as C) optional via nullptr.
// Tile 128x128, BK=32. 4 waves in 2x2; each wave owns a 64x64 sub-tile
// (4x4 fragments of 16x16, v_mfma_f32_16x16x32_f16).
template <bool BT, bool GELU>
__global__ __launch_bounds__(256) void gemm_kernel(
    const float* __restrict__ A, const float* __restrict__ Bm,
    const float* __restrict__ bias, const float* __restrict__ res,
    float* __restrict__ C, int M, int N, int K) {
  constexpr int LDT = 40;  // 32 + 8 pad: ds_read_b128 frag loads bank-uniform
  __shared__ __align__(16) _Float16 As[128][LDT];  // [m][k]
  __shared__ __align__(16) _Float16 Bs[128][LDT];  // [n][k]
  const int t    = threadIdx.x;
  const int lane = t & 63;
  const int wave = t >> 6;
  const int wm   = (wave >> 1) * 64;  // wave's m-offset in tile
  const int wn   = (wave & 1) * 64;   // wave's n-offset in tile
  const int m0 = blockIdx.y * 128, n0 = blockIdx.x * 128;
  const int lr = lane & 15;        // fragment row (A) / col (B)
  const int lk = (lane >> 4) * 8;  // fragment k-offset

  floatx4 acc[4][4] = {};

  for (int k0 = 0; k0 < K; k0 += 32) {
    // ---- stage A tile: 128 rows x 32 k (K contiguous in source) ----
    #pragma unroll
    for (int ff = 0; ff < 4; ++ff) {
      int f = t + ff * 256;            // 1024 half4-chunks
      int row = f >> 3, c4 = (f & 7) * 4;
      float4 a4 = *(const float4*)(A + (size_t)(m0 + row) * K + k0 + c4);
      half4_t h;
      h[0] = (_Float16)a4.x; h[1] = (_Float16)a4.y;
      h[2] = (_Float16)a4.z; h[3] = (_Float16)a4.w;
      *(half4_t*)&As[row][c4] = h;
    }
    // ---- stage B tile -> Bs[n][k] ----
    if (!BT) {
      // source [K,N]: read along N, transpose into Bs (scalar fp16 writes)
      #pragma unroll
      for (int ff = 0; ff < 4; ++ff) {
        int f = t + ff * 256;
        int kr = f >> 5, nc = (f & 31) * 4;
        float4 b4 = *(const float4*)(Bm + (size_t)(k0 + kr) * N + n0 + nc);
        Bs[nc + 0][kr] = (_Float16)b4.x;
        Bs[nc + 1][kr] = (_Float16)b4.y;
        Bs[nc + 2][kr] = (_Float16)b4.z;
        Bs[nc + 3][kr] = (_Float16)b4.w;
      }
    } else {
      // source [N,K]: K contiguous at fixed n — direct copy; guard n (logits tail)
      #pragma unroll
      for (int ff = 0; ff < 4; ++ff) {
        int f = t + ff * 256;
        int row = f >> 3, c4 = (f & 7) * 4;
        float4 b4 = make_float4(0.f, 0.f, 0.f, 0.f);
        if (n0 + row < N)
          b4 = *(const float4*)(Bm + (size_t)(n0 + row) * K + k0 + c4);
        half4_t h;
        h[0] = (_Float16)b4.x; h[1] = (_Float16)b4.y;
        h[2] = (_Float16)b4.z; h[3] = (_Float16)b4.w;
        *(half4_t*)&Bs[row][c4] = h;
      }
    }
    __syncthreads();

    // ---- fragments + MFMA (one K=32 step) ----
    half8_t af[4], bf[4];
    #pragma unroll
    for (int mi = 0; mi < 4; ++mi)
      af[mi] = *(const half8_t*)&As[wm + mi * 16 + lr][lk];
    #pragma unroll
    for (int ni = 0; ni < 4; ++ni)
      bf[ni] = *(const half8_t*)&Bs[wn + ni * 16 + lr][lk];
    #pragma unroll
    for (int mi = 0; mi < 4; ++mi)
      #pragma unroll
      for (int ni = 0; ni < 4; ++ni)
        acc[mi][ni] = __builtin_amdgcn_mfma_f32_16x16x32_f16(
            af[mi], bf[ni], acc[mi][ni], 0, 0, 0);
    __syncthreads();
  }

  // ---- epilogue: C/D layout col=lane&15, row=(lane>>4)*4+reg (m89-verified) ----
  const int cr = (lane >> 4) * 4;
  #pragma unroll
  for (int mi = 0; mi < 4; ++mi) {
    #pragma unroll
    for (int ni = 0; ni < 4; ++ni) {
      int n = n0 + wn + ni * 16 + lr;
      if (BT && n >= N) continue;
      floatx4 v = acc[mi][ni];
      #pragma unroll
      for (int i = 0; i < 4; ++i) {
        int m = m0 + wm + mi * 16 + cr + i;
        float vv = v[i];
        if (bias) vv += bias[n];
        if (res)  vv += res[(size_t)m * N + n];
        if (GELU) vv = 0.5f * vv * (1.f + erff(vv * 0.70710678118f));
        C[(size_t)m * N + n] = vv;
      }
    }
  }
}

// ---------------- launcher ----------------
extern "C" void kernel_launch(void* const* d_in, const int* in_sizes, int n_in,
                              void* d_out, int out_size, void* d_ws, size_t ws_size,
                              hipStream_t stream) {
  const int*   idx   = (const int*)d_in[0];
  const float* wte   = (const float*)d_in[1];
  const float* pos   = (const float*)d_in[2];
  const float* ln1g  = (const float*)d_in[3];
  const float* ln1b  = (const float*)d_in[4];
  const float* qkvw  = (const float*)d_in[5];
  const float* qkvb  = (const float*)d_in[6];
  const float* projw = (const float*)d_in[7];
  const float* projb = (const float*)d_in[8];
  const float* ln2g  = (const float*)d_in[9];
  const float* ln2b  = (const float*)d_in[10];
  const float* fc1w  = (const float*)d_in[11];
  const float* fc1b  = (const float*)d_in[12];
  const float* fc2w  = (const float*)d_in[13];
  const float* fc2b  = (const float*)d_in[14];
  const float* lnfg  = (const float*)d_in[15];
  const float* lnfb  = (const float*)d_in[16];
  float* out = (float*)d_out;

  float* ws   = (float*)d_ws;
  float* x    = ws;                           // [NT, D]
  float* hbuf = x    + (size_t)NT * D;        // [NT, D]
  float* obuf = hbuf + (size_t)NT * D;        // [NT, D]
  float* big  = obuf + (size_t)NT * D;        // [NT, 4D] (also holds qkv [NT,3D])

  embed_kernel<<<NT, 256, 0, stream>>>(idx, wte, pos, x);

  for (int l = 0; l < NL; ++l) {
    // ln1
    ln_kernel<<<NT, 256, 0, stream>>>(x, ln1g + (size_t)l * D, ln1b + (size_t)l * D, hbuf);
    // qkv = h @ qkv_w + qkv_b   [NT, 3D]
    gemm_kernel<false, false><<<dim3((3 * D) / 128, NT / 128), 256, 0, stream>>>(
        hbuf, qkvw + (size_t)l * D * 3 * D, qkvb + (size_t)l * 3 * D, nullptr,
        big, NT, 3 * D, D);
    // attention
    attn_kernel<<<dim3(T, NH, BATCH), 64, 0, stream>>>(big, obuf);
    // x = x + o @ proj_w + proj_b
    gemm_kernel<false, false><<<dim3(D / 128, NT / 128), 256, 0, stream>>>(
        obuf, projw + (size_t)l * D * D, projb + (size_t)l * D, x,
        x, NT, D, D);
    // ln2
    ln_kernel<<<NT, 256, 0, stream>>>(x, ln2g + (size_t)l * D, ln2b + (size_t)l * D, hbuf);
    // fc1 + GELU -> big [NT, 4D]
    gemm_kernel<false, true><<<dim3((4 * D) / 128, NT / 128), 256, 0, stream>>>(
        hbuf, fc1w + (size_t)l * D * 4 * D, fc1b + (size_t)l * 4 * D, nullptr,
        big, NT, 4 * D, D);
    // x = x + gelu @ fc2_w + fc2_b
    gemm_kernel<false, false><<<dim3(D / 128, NT / 128), 256, 0, stream>>>(
        big, fc2w + (size_t)l * 4 * D * D, fc2b + (size_t)l * D, x,
        x, NT, D, 4 * D);
  }

  // final LN
  ln_kernel<<<NT, 256, 0, stream>>>(x, lnfg, lnfb, hbuf);
  // logits = h @ wte^T   [NT, V]
  gemm_kernel<true, false><<<dim3((V + 127) / 128, NT / 128), 256, 0, stream>>>(
      hbuf, wte, nullptr, nullptr, out, NT, V, D);
}

// Round 2
// 11153.840 us; speedup vs baseline: 1.8594x; 1.3009x over previous
//
#include <hip/hip_runtime.h>
#include <math.h>

#define D 768
#define T 1024
#define BATCH 2
#define NH 12
#define NL 12
#define V 50257
#define NT 2048  // BATCH*T

typedef _Float16 half4_t __attribute__((ext_vector_type(4)));
typedef _Float16 half8_t __attribute__((ext_vector_type(8)));
typedef float floatx4 __attribute__((ext_vector_type(4)));

// ---------------- wave helpers ----------------
__device__ inline float wave_reduce_sum(float v) {
  #pragma unroll
  for (int off = 32; off > 0; off >>= 1) v += __shfl_xor(v, off, 64);
  return v;
}
__device__ inline float wave_reduce_max(float v) {
  #pragma unroll
  for (int off = 32; off > 0; off >>= 1) v = fmaxf(v, __shfl_xor(v, off, 64));
  return v;
}

// direct HBM->LDS, 16B per lane (1KB per wave-instruction)
__device__ __forceinline__ void gld16(const _Float16* g, _Float16* l) {
  __builtin_amdgcn_global_load_lds(
      (const __attribute__((address_space(1))) unsigned int*)g,
      (__attribute__((address_space(3))) unsigned int*)l, 16, 0, 0);
}

// ---------------- embedding ----------------
__global__ __launch_bounds__(256) void embed_kernel(const int* __restrict__ idx,
    const float* __restrict__ wte, const float* __restrict__ pos,
    float* __restrict__ x) {
  int row = blockIdx.x;                 // 0..NT-1
  int tok = idx[row];
  int tp  = row & (T - 1);
  const float* ws = wte + (size_t)tok * D;
  const float* ps = pos + (size_t)tp * D;
  float* xr = x + (size_t)row * D;
  for (int i = threadIdx.x; i < D; i += 256) xr[i] = ws[i] + ps[i];
}

// ---------------- fp32 -> fp16 bulk convert (wte) ----------------
__global__ __launch_bounds__(256) void cvt16_kernel(const float* __restrict__ src,
    _Float16* __restrict__ dst, int n4) {
  int i = blockIdx.x * 256 + threadIdx.x;
  int stride = gridDim.x * 256;
  for (; i < n4; i += stride) {
    float4 v = ((const float4*)src)[i];
    half4_t h;
    h[0] = (_Float16)v.x; h[1] = (_Float16)v.y;
    h[2] = (_Float16)v.z; h[3] = (_Float16)v.w;
    ((half4_t*)dst)[i] = h;
  }
}

// ---------------- per-layer weight convert+transpose: [K,N]f32 -> [N,K]f16 ----
// tiles: qkv 24x72=1728; proj 24x24=576; fc1 24x96=2304; fc2 96x24=2304; total 6912
__global__ __launch_bounds__(256) void wconv_kernel(
    const float* __restrict__ qkvw, const float* __restrict__ projw,
    const float* __restrict__ fc1w, const float* __restrict__ fc2w,
    _Float16* __restrict__ q16, _Float16* __restrict__ p16,
    _Float16* __restrict__ f116, _Float16* __restrict__ f216) {
  int id = blockIdx.x;
  const float* src; _Float16* dst; int K, N, tn;
  if (id < 1728)      { src = qkvw;  dst = q16;  K = 768;  N = 2304; tn = id; }
  else if (id < 2304) { src = projw; dst = p16;  K = 768;  N = 768;  tn = id - 1728; }
  else if (id < 4608) { src = fc1w;  dst = f116; K = 768;  N = 3072; tn = id - 2304; }
  else                { src = fc2w;  dst = f216; K = 3072; N = 768;  tn = id - 4608; }
  int ntn = N >> 5;
  int tc = (tn % ntn) * 32;   // n0
  int tr = (tn / ntn) * 32;   // k0
  __shared__ float tile[32][33];
  int tx = threadIdx.x & 31, ty = threadIdx.x >> 5;
  #pragma unroll
  for (int j = 0; j < 4; ++j)
    tile[ty + 8 * j][tx] = src[(size_t)(tr + ty + 8 * j) * N + tc + tx];
  __syncthreads();
  #pragma unroll
  for (int j = 0; j < 4; ++j)
    dst[(size_t)(tc + ty + 8 * j) * K + tr + tx] = (_Float16)tile[tx][ty + 8 * j];
}

// ---------------- layernorm (fp32 in, fp16 out) ----------------
__global__ __launch_bounds__(256) void ln_kernel(const float* __restrict__ x,
    const float* __restrict__ g, const float* __restrict__ bta,
    _Float16* __restrict__ y) {
  int row = blockIdx.x;
  const float* xr = x + (size_t)row * D;
  _Float16* yr = y + (size_t)row * D;
  int t = threadIdx.x, lane = t & 63, wid = t >> 6;
  __shared__ float red[4];
  __shared__ float s_mean, s_rstd;

  float s = 0.f;
  for (int i = t; i < D; i += 256) s += xr[i];
  s = wave_reduce_sum(s);
  if (lane == 0) red[wid] = s;
  __syncthreads();
  if (t == 0) s_mean = (red[0] + red[1] + red[2] + red[3]) * (1.f / D);
  __syncthreads();
  float mean = s_mean;

  float v = 0.f;
  for (int i = t; i < D; i += 256) { float d = xr[i] - mean; v += d * d; }
  v = wave_reduce_sum(v);
  if (lane == 0) red[wid] = v;
  __syncthreads();
  if (t == 0) s_rstd = rsqrtf((red[0] + red[1] + red[2] + red[3]) * (1.f / D) + 1e-5f);
  __syncthreads();
  float rstd = s_rstd;

  for (int i = t; i < D; i += 256)
    yr[i] = (_Float16)((xr[i] - mean) * rstd * g[i] + bta[i]);
}

// ---------------- attention (one wave per (b,h,q-row)); fp16 out ----------------
__global__ __launch_bounds__(64) void attn_kernel(const float* __restrict__ qkv,
                                                  _Float16* __restrict__ o) {
  const int tq   = blockIdx.x;
  const int h    = blockIdx.y;
  const int b    = blockIdx.z;
  const int lane = threadIdx.x;
  __shared__ float qs[64];
  __shared__ float s[T];
  const int RS = 3 * D;  // qkv row stride

  const float* qp = qkv + (size_t)(b * T + tq) * RS + h * 64;
  qs[lane] = qp[lane];
  __syncthreads();

  // scores (causal: keys 0..tq)
  for (int k = lane; k <= tq; k += 64) {
    const float* kp = qkv + (size_t)(b * T + k) * RS + D + h * 64;
    float acc = 0.f;
    #pragma unroll
    for (int d2 = 0; d2 < 64; ++d2) acc = fmaf(qs[d2], kp[d2], acc);
    s[k] = acc * 0.125f;  // 1/sqrt(64)
  }
  __syncthreads();

  float m = -1e30f;
  for (int k = lane; k <= tq; k += 64) m = fmaxf(m, s[k]);
  m = wave_reduce_max(m);
  float sum = 0.f;
  for (int k = lane; k <= tq; k += 64) { float p = expf(s[k] - m); s[k] = p; sum += p; }
  sum = wave_reduce_sum(sum);
  __syncthreads();
  float inv = 1.f / sum;

  // PV: lane owns output dim `lane`
  const float* vbase = qkv + (size_t)(b * T) * RS + 2 * D + h * 64 + lane;
  float acc = 0.f;
  for (int k = 0; k <= tq; ++k) acc = fmaf(s[k], vbase[(size_t)k * RS], acc);
  o[(size_t)(b * T + tq) * D + h * 64 + lane] = (_Float16)(acc * inv);
}

// ---------------- fp16 MFMA GEMM, m97 structure ----------------
// C[M,N] = A[M,K] @ Bt[N,K]^T (+bias,+res,+GELU). A,Bt fp16 K-contiguous.
// 128x128 tile, BK=32, 4 waves 2x2, global_load_lds width-16 staging,
// linear [128][32] fp16 LDS (64B rows -> conflict-free b128 frag reads).
// M%128==0, K%32==0 required; N tail handled by row-clamp + epilogue guard.
template <bool GELU, typename OutT>
__global__ __launch_bounds__(256) void gemm16_kernel(
    const _Float16* __restrict__ A, const _Float16* __restrict__ Bt,
    const float* __restrict__ bias, const float* __restrict__ res,
    OutT* __restrict__ C, int M, int N, int K) {
  __shared__ __align__(16) _Float16 As[128][32];
  __shared__ __align__(16) _Float16 Bs[128][32];
  const int t = threadIdx.x;
  const int lane = t & 63, wave = t >> 6;

  // XCD-aware swizzle (all launches have nwg % 8 == 0)
  const int gx = gridDim.x;
  const int nwg = gx * gridDim.y;
  int id = blockIdx.y * gx + blockIdx.x;
  id = (id & 7) * (nwg >> 3) + (id >> 3);
  const int n0 = (id % gx) * 128;
  const int m0 = (id / gx) * 128;

  const int wm = (wave >> 1) * 64, wn = (wave & 1) * 64;
  const int lr = lane & 15;            // frag row (A) / col (B)
  const int lk = (lane >> 4) * 8;      // frag k-offset (halves)

  // staging: wave w covers tile rows 32w..32w+31; 2 insts of 16 rows each
  const int srow = lane >> 2;          // 0..15
  const int scol = (lane & 3) * 8;     // halves: 0,8,16,24 (16B chunks)
  const _Float16* a_src0 = A + (size_t)(m0 + wave * 32 + srow) * K + scol;
  const _Float16* a_src1 = a_src0 + (size_t)16 * K;
  const int bn0 = min(n0 + wave * 32 + srow, N - 1);       // clamp (logits tail)
  const int bn1 = min(n0 + wave * 32 + 16 + srow, N - 1);
  const _Float16* b_src0 = Bt + (size_t)bn0 * K + scol;
  const _Float16* b_src1 = Bt + (size_t)bn1 * K + scol;
  _Float16* a_dst0 = &As[wave * 32][0];
  _Float16* a_dst1 = &As[wave * 32 + 16][0];
  _Float16* b_dst0 = &Bs[wave * 32][0];
  _Float16* b_dst1 = &Bs[wave * 32 + 16][0];

  floatx4 acc[4][4] = {};

  for (int k0 = 0; k0 < K; k0 += 32) {
    gld16(a_src0 + k0, a_dst0);
    gld16(a_src1 + k0, a_dst1);
    gld16(b_src0 + k0, b_dst0);
    gld16(b_src1 + k0, b_dst1);
    __syncthreads();   // vmcnt(0) drained by compiler before barrier

    half8_t af[4], bf[4];
    #pragma unroll
    for (int mi = 0; mi < 4; ++mi)
      af[mi] = *(const half8_t*)&As[wm + mi * 16 + lr][lk];
    #pragma unroll
    for (int ni = 0; ni < 4; ++ni)
      bf[ni] = *(const half8_t*)&Bs[wn + ni * 16 + lr][lk];
    #pragma unroll
    for (int mi = 0; mi < 4; ++mi)
      #pragma unroll
      for (int ni = 0; ni < 4; ++ni)
        acc[mi][ni] = __builtin_amdgcn_mfma_f32_16x16x32_f16(
            af[mi], bf[ni], acc[mi][ni], 0, 0, 0);
    __syncthreads();   // frag reads done before next-iter staging overwrites
  }

  // epilogue: C/D layout col=lane&15, row=(lane>>4)*4+reg
  const int cr = (lane >> 4) * 4;
  #pragma unroll
  for (int mi = 0; mi < 4; ++mi) {
    #pragma unroll
    for (int ni = 0; ni < 4; ++ni) {
      int n = n0 + wn + ni * 16 + lr;
      if (n >= N) continue;
      floatx4 v = acc[mi][ni];
      #pragma unroll
      for (int i = 0; i < 4; ++i) {
        int m = m0 + wm + mi * 16 + cr + i;
        float vv = v[i];
        if (bias) vv += bias[n];
        if (res)  vv += res[(size_t)m * N + n];
        if (GELU) vv = 0.5f * vv * (1.f + erff(vv * 0.70710678118f));
        C[(size_t)m * N + n] = (OutT)vv;
      }
    }
  }
}

// ---------------- launcher ----------------
extern "C" void kernel_launch(void* const* d_in, const int* in_sizes, int n_in,
                              void* d_out, int out_size, void* d_ws, size_t ws_size,
                              hipStream_t stream) {
  const int*   idx   = (const int*)d_in[0];
  const float* wte   = (const float*)d_in[1];
  const float* pos   = (const float*)d_in[2];
  const float* ln1g  = (const float*)d_in[3];
  const float* ln1b  = (const float*)d_in[4];
  const float* qkvw  = (const float*)d_in[5];
  const float* qkvb  = (const float*)d_in[6];
  const float* projw = (const float*)d_in[7];
  const float* projb = (const float*)d_in[8];
  const float* ln2g  = (const float*)d_in[9];
  const float* ln2b  = (const float*)d_in[10];
  const float* fc1w  = (const float*)d_in[11];
  const float* fc1b  = (const float*)d_in[12];
  const float* fc2w  = (const float*)d_in[13];
  const float* fc2b  = (const float*)d_in[14];
  const float* lnfg  = (const float*)d_in[15];
  const float* lnfb  = (const float*)d_in[16];
  float* out = (float*)d_out;

  // ---- workspace layout ----
  float* ws = (float*)d_ws;
  float* x     = ws;                              // [NT, D] f32 residual
  float* big32 = x + (size_t)NT * D;              // [NT, 3D] f32 qkv (attn input)
  _Float16* big16  = (_Float16*)big32;            // [NT, 4D] f16 gelu out (aliases
                                                  //  big32: disjoint lifetimes)
  _Float16* hbuf16 = (_Float16*)(big32 + (size_t)NT * 4 * D);  // [NT, D] f16
  _Float16* obuf16 = hbuf16 + (size_t)NT * D;     // [NT, D] f16
  _Float16* q16    = obuf16 + (size_t)NT * D;     // [2304, 768]
  _Float16* p16    = q16  + (size_t)2304 * 768;   // [768, 768]
  _Float16* f116   = p16  + (size_t)768 * 768;    // [3072, 768]
  _Float16* f216   = f116 + (size_t)3072 * 768;   // [768, 3072]
  _Float16* wte16  = f216 + (size_t)768 * 3072;   // [V, D]

  // wte -> fp16 once (77MB, becomes L3-resident for the logits GEMM)
  cvt16_kernel<<<2048, 256, 0, stream>>>(wte, wte16, (V * D) / 4);

  embed_kernel<<<NT, 256, 0, stream>>>(idx, wte, pos, x);

  for (int l = 0; l < NL; ++l) {
    // convert+transpose this layer's weights to fp16 [N,K]
    wconv_kernel<<<6912, 256, 0, stream>>>(
        qkvw + (size_t)l * D * 3 * D, projw + (size_t)l * D * D,
        fc1w + (size_t)l * D * 4 * D, fc2w + (size_t)l * 4 * D * D,
        q16, p16, f116, f216);
    // ln1 -> fp16
    ln_kernel<<<NT, 256, 0, stream>>>(x, ln1g + (size_t)l * D, ln1b + (size_t)l * D, hbuf16);
    // qkv = h @ qkv_w + qkv_b  -> big32 (fp32 for attn)
    gemm16_kernel<false, float><<<dim3(18, 16), 256, 0, stream>>>(
        hbuf16, q16, qkvb + (size_t)l * 3 * D, nullptr, big32, NT, 3 * D, D);
    // attention -> obuf16
    attn_kernel<<<dim3(T, NH, BATCH), 64, 0, stream>>>(big32, obuf16);
    // x = x + o @ proj_w + proj_b
    gemm16_kernel<false, float><<<dim3(6, 16), 256, 0, stream>>>(
        obuf16, p16, projb + (size_t)l * D, x, x, NT, D, D);
    // ln2 -> fp16
    ln_kernel<<<NT, 256, 0, stream>>>(x, ln2g + (size_t)l * D, ln2b + (size_t)l * D, hbuf16);
    // fc1 + GELU -> big16 (fp16)
    gemm16_kernel<true, _Float16><<<dim3(24, 16), 256, 0, stream>>>(
        hbuf16, f116, fc1b + (size_t)l * 4 * D, nullptr, big16, NT, 4 * D, D);
    // x = x + gelu @ fc2_w + fc2_b
    gemm16_kernel<false, float><<<dim3(6, 16), 256, 0, stream>>>(
        big16, f216, fc2b + (size_t)l * D, x, x, NT, D, 4 * D);
  }

  // final LN -> fp16
  ln_kernel<<<NT, 256, 0, stream>>>(x, lnfg, lnfb, hbuf16);
  // logits = h @ wte^T   [NT, V]
  gemm16_kernel<false, float><<<dim3((V + 127) / 128, 16), 256, 0, stream>>>(
      hbuf16, wte16, nullptr, nullptr, out, NT, V, D);
}

// Round 3
// 3751.630 us; speedup vs baseline: 5.5281x; 2.9731x over previous
//
#include <hip/hip_runtime.h>
#include <math.h>

#define D 768
#define T 1024
#define BATCH 2
#define NH 12
#define NL 12
#define V 50257
#define NT 2048  // BATCH*T

typedef _Float16 half4_t __attribute__((ext_vector_type(4)));
typedef _Float16 half8_t __attribute__((ext_vector_type(8)));
typedef float floatx4 __attribute__((ext_vector_type(4)));

// ---------------- wave helpers ----------------
__device__ inline float wave_reduce_sum(float v) {
  #pragma unroll
  for (int off = 32; off > 0; off >>= 1) v += __shfl_xor(v, off, 64);
  return v;
}

// direct HBM->LDS, 16B per lane (1KB per wave-instruction)
__device__ __forceinline__ void gld16(const _Float16* g, _Float16* l) {
  __builtin_amdgcn_global_load_lds(
      (const __attribute__((address_space(1))) unsigned int*)g,
      (__attribute__((address_space(3))) unsigned int*)l, 16, 0, 0);
}

// ---------------- embedding ----------------
__global__ __launch_bounds__(256) void embed_kernel(const int* __restrict__ idx,
    const float* __restrict__ wte, const float* __restrict__ pos,
    float* __restrict__ x) {
  int row = blockIdx.x;                 // 0..NT-1
  int tok = idx[row];
  int tp  = row & (T - 1);
  const float* ws = wte + (size_t)tok * D;
  const float* ps = pos + (size_t)tp * D;
  float* xr = x + (size_t)row * D;
  for (int i = threadIdx.x; i < D; i += 256) xr[i] = ws[i] + ps[i];
}

// ---------------- fp32 -> fp16 bulk convert (wte) ----------------
__global__ __launch_bounds__(256) void cvt16_kernel(const float* __restrict__ src,
    _Float16* __restrict__ dst, int n4) {
  int i = blockIdx.x * 256 + threadIdx.x;
  int stride = gridDim.x * 256;
  for (; i < n4; i += stride) {
    float4 v = ((const float4*)src)[i];
    half4_t h;
    h[0] = (_Float16)v.x; h[1] = (_Float16)v.y;
    h[2] = (_Float16)v.z; h[3] = (_Float16)v.w;
    ((half4_t*)dst)[i] = h;
  }
}

// ---------------- per-layer weight convert+transpose: [K,N]f32 -> [N,K]f16 ----
__global__ __launch_bounds__(256) void wconv_kernel(
    const float* __restrict__ qkvw, const float* __restrict__ projw,
    const float* __restrict__ fc1w, const float* __restrict__ fc2w,
    _Float16* __restrict__ q16, _Float16* __restrict__ p16,
    _Float16* __restrict__ f116, _Float16* __restrict__ f216) {
  int id = blockIdx.x;
  const float* src; _Float16* dst; int K, N, tn;
  if (id < 1728)      { src = qkvw;  dst = q16;  K = 768;  N = 2304; tn = id; }
  else if (id < 2304) { src = projw; dst = p16;  K = 768;  N = 768;  tn = id - 1728; }
  else if (id < 4608) { src = fc1w;  dst = f116; K = 768;  N = 3072; tn = id - 2304; }
  else                { src = fc2w;  dst = f216; K = 3072; N = 768;  tn = id - 4608; }
  int ntn = N >> 5;
  int tc = (tn % ntn) * 32;   // n0
  int tr = (tn / ntn) * 32;   // k0
  __shared__ float tile[32][33];
  int tx = threadIdx.x & 31, ty = threadIdx.x >> 5;
  #pragma unroll
  for (int j = 0; j < 4; ++j)
    tile[ty + 8 * j][tx] = src[(size_t)(tr + ty + 8 * j) * N + tc + tx];
  __syncthreads();
  #pragma unroll
  for (int j = 0; j < 4; ++j)
    dst[(size_t)(tc + ty + 8 * j) * K + tr + tx] = (_Float16)tile[tx][ty + 8 * j];
}

// ---------------- layernorm (fp32 in, fp16 out) ----------------
__global__ __launch_bounds__(256) void ln_kernel(const float* __restrict__ x,
    const float* __restrict__ g, const float* __restrict__ bta,
    _Float16* __restrict__ y) {
  int row = blockIdx.x;
  const float* xr = x + (size_t)row * D;
  _Float16* yr = y + (size_t)row * D;
  int t = threadIdx.x, lane = t & 63, wid = t >> 6;
  __shared__ float red[4];
  __shared__ float s_mean, s_rstd;

  float s = 0.f;
  for (int i = t; i < D; i += 256) s += xr[i];
  s = wave_reduce_sum(s);
  if (lane == 0) red[wid] = s;
  __syncthreads();
  if (t == 0) s_mean = (red[0] + red[1] + red[2] + red[3]) * (1.f / D);
  __syncthreads();
  float mean = s_mean;

  float v = 0.f;
  for (int i = t; i < D; i += 256) { float d = xr[i] - mean; v += d * d; }
  v = wave_reduce_sum(v);
  if (lane == 0) red[wid] = v;
  __syncthreads();
  if (t == 0) s_rstd = rsqrtf((red[0] + red[1] + red[2] + red[3]) * (1.f / D) + 1e-5f);
  __syncthreads();
  float rstd = s_rstd;

  for (int i = t; i < D; i += 256)
    yr[i] = (_Float16)((xr[i] - mean) * rstd * g[i] + bta[i]);
}

// ---------------- MFMA flash attention ----------------
// Grid (T/64, NH, BATCH), 256 threads (4 waves). Block handles 64 q-rows
// (long blocks launched first); wave owns 16 q-rows, Q pre-scaled in regs.
// Per 64-key tile: stage K [2][64][32] and V^T [2][64][32] fp16 via
// global_load_lds; QK^T (8 MFMA) -> online softmax in C-layout -> P via
// per-wave LDS [16][72] -> PV (8 MFMA), fp32 O accum.
__global__ __launch_bounds__(256) void attn_kernel(
    const _Float16* __restrict__ qkv,   // [NT, 3D] fp16 (Q at 0, K at D; V third unused)
    const _Float16* __restrict__ vt,    // [B*NH*64, T] fp16 (V transposed)
    _Float16* __restrict__ o) {         // [NT, D] fp16
  const int qt   = (int)gridDim.x - 1 - (int)blockIdx.x;
  const int h    = blockIdx.y;
  const int b    = blockIdx.z;
  const int tid  = threadIdx.x;
  const int lane = tid & 63, wave = tid >> 6;
  const int lr = lane & 15, g = lane >> 4;
  const int lk = g * 8;   // frag k-offset (halves)
  const int cr = g * 4;   // C-fragment row base

  __shared__ __align__(16) _Float16 Ks[2][64][32];   // [dstep][key][d-half]
  __shared__ __align__(16) _Float16 Vs[2][64][32];   // [kstep][d][key-half]
  __shared__ __align__(16) _Float16 Pl[4][16][72];   // per-wave P[q][k]

  const int RS = 3 * D;
  const int q0 = qt * 64 + wave * 16;

  // Q fragments (A-layout: lane holds Q[q=lr][d=lk+j(+32)]), pre-scaled by 1/8
  const _Float16* qrow = qkv + (size_t)(b * T + q0 + lr) * RS + h * 64;
  half8_t aq0 = *(const half8_t*)(qrow + lk);
  half8_t aq1 = *(const half8_t*)(qrow + 32 + lk);
  #pragma unroll
  for (int j = 0; j < 8; ++j) { aq0[j] *= (_Float16)0.125f; aq1[j] *= (_Float16)0.125f; }

  // staging: wave stages rows wave*16..+15 of each LDS array
  const int sr = wave * 16 + (lane >> 2);
  const int sc = (lane & 3) * 8;
  const _Float16* ksrc = qkv + (size_t)(b * T + sr) * RS + D + h * 64 + sc;
  const _Float16* vsrc = vt + (size_t)((b * NH + h) * 64 + sr) * T + sc;
  _Float16* kdst0 = &Ks[0][wave * 16][0];
  _Float16* kdst1 = &Ks[1][wave * 16][0];
  _Float16* vdst0 = &Vs[0][wave * 16][0];
  _Float16* vdst1 = &Vs[1][wave * 16][0];

  floatx4 oa[4] = {};                       // O[q=cr+i][d=dc*16+lr]
  float m_r[4] = {-1e30f, -1e30f, -1e30f, -1e30f};
  float l_r[4] = {0.f, 0.f, 0.f, 0.f};

  for (int kt = 0; kt <= qt; ++kt) {
    const _Float16* kp = ksrc + (size_t)(kt * 64) * RS;
    gld16(kp, kdst0);
    gld16(kp + 32, kdst1);
    gld16(vsrc + kt * 64, vdst0);
    gld16(vsrc + kt * 64 + 32, vdst1);
    __syncthreads();

    // QK^T: S[q=cr+i][k=kc*16+lr]
    floatx4 s4[4];
    #pragma unroll
    for (int kc = 0; kc < 4; ++kc) {
      half8_t bk0 = *(const half8_t*)&Ks[0][kc * 16 + lr][lk];
      half8_t bk1 = *(const half8_t*)&Ks[1][kc * 16 + lr][lk];
      floatx4 z = {};
      z = __builtin_amdgcn_mfma_f32_16x16x32_f16(aq0, bk0, z, 0, 0, 0);
      z = __builtin_amdgcn_mfma_f32_16x16x32_f16(aq1, bk1, z, 0, 0, 0);
      s4[kc] = z;
    }
    if (kt == qt) {  // causal mask on diagonal tile
      #pragma unroll
      for (int kc = 0; kc < 4; ++kc)
        #pragma unroll
        for (int i = 0; i < 4; ++i)
          if (kc * 16 + lr > wave * 16 + cr + i) s4[kc][i] = -1e30f;
    }

    // online softmax: row-reduce = in-lane over kc + butterfly over low 4 lane bits
    float alpha[4], psum[4];
    #pragma unroll
    for (int i = 0; i < 4; ++i) {
      float v = fmaxf(fmaxf(s4[0][i], s4[1][i]), fmaxf(s4[2][i], s4[3][i]));
      #pragma unroll
      for (int off = 1; off < 16; off <<= 1) v = fmaxf(v, __shfl_xor(v, off, 64));
      float mn = fmaxf(m_r[i], v);
      alpha[i] = __expf(m_r[i] - mn);
      m_r[i] = mn;
      psum[i] = 0.f;
    }
    #pragma unroll
    for (int kc = 0; kc < 4; ++kc)
      #pragma unroll
      for (int i = 0; i < 4; ++i) {
        float p = __expf(s4[kc][i] - m_r[i]);
        psum[i] += p;
        Pl[wave][cr + i][kc * 16 + lr] = (_Float16)p;
      }
    #pragma unroll
    for (int i = 0; i < 4; ++i) {
      float s = psum[i];
      #pragma unroll
      for (int off = 1; off < 16; off <<= 1) s += __shfl_xor(s, off, 64);
      l_r[i] = l_r[i] * alpha[i] + s;
    }
    #pragma unroll
    for (int dc = 0; dc < 4; ++dc)
      #pragma unroll
      for (int i = 0; i < 4; ++i) oa[dc][i] *= alpha[i];

    // PV: A = P (per-wave LDS), B = V^T tiles
    half8_t ap0 = *(const half8_t*)&Pl[wave][lr][lk];
    half8_t ap1 = *(const half8_t*)&Pl[wave][lr][32 + lk];
    #pragma unroll
    for (int dc = 0; dc < 4; ++dc) {
      half8_t bv0 = *(const half8_t*)&Vs[0][dc * 16 + lr][lk];
      half8_t bv1 = *(const half8_t*)&Vs[1][dc * 16 + lr][lk];
      oa[dc] = __builtin_amdgcn_mfma_f32_16x16x32_f16(ap0, bv0, oa[dc], 0, 0, 0);
      oa[dc] = __builtin_amdgcn_mfma_f32_16x16x32_f16(ap1, bv1, oa[dc], 0, 0, 0);
    }
    __syncthreads();
  }

  _Float16* orow = o + (size_t)(b * T + q0) * D + h * 64;
  #pragma unroll
  for (int i = 0; i < 4; ++i) {
    float inv = 1.f / l_r[i];
    #pragma unroll
    for (int dc = 0; dc < 4; ++dc)
      orow[(size_t)(cr + i) * D + dc * 16 + lr] = (_Float16)(oa[dc][i] * inv);
  }
}

// ---------------- fp16 MFMA GEMM, m97 structure ----------------
// C[M,N] = A[M,K] @ Bt[N,K]^T (+bias,+res,+GELU). A,Bt fp16 K-contiguous.
// VT: for n>=2D (V third of qkv), write transposed into vt[B*NH*64][T] instead.
template <bool GELU, bool VT, typename OutT>
__global__ __launch_bounds__(256) void gemm16_kernel(
    const _Float16* __restrict__ A, const _Float16* __restrict__ Bt,
    const float* __restrict__ bias, const float* __restrict__ res,
    OutT* __restrict__ C, _Float16* __restrict__ vt, int M, int N, int K) {
  __shared__ __align__(16) _Float16 As[128][32];
  __shared__ __align__(16) _Float16 Bs[128][32];
  const int t = threadIdx.x;
  const int lane = t & 63, wave = t >> 6;

  // XCD-aware swizzle (all launches have nwg % 8 == 0)
  const int gx = gridDim.x;
  const int nwg = gx * gridDim.y;
  int id = blockIdx.y * gx + blockIdx.x;
  id = (id & 7) * (nwg >> 3) + (id >> 3);
  const int n0 = (id % gx) * 128;
  const int m0 = (id / gx) * 128;

  const int wm = (wave >> 1) * 64, wn = (wave & 1) * 64;
  const int lr = lane & 15;            // frag row (A) / col (B)
  const int lk = (lane >> 4) * 8;      // frag k-offset (halves)

  const int srow = lane >> 2;          // 0..15
  const int scol = (lane & 3) * 8;     // halves
  const _Float16* a_src0 = A + (size_t)(m0 + wave * 32 + srow) * K + scol;
  const _Float16* a_src1 = a_src0 + (size_t)16 * K;
  const int bn0 = min(n0 + wave * 32 + srow, N - 1);       // clamp (logits tail)
  const int bn1 = min(n0 + wave * 32 + 16 + srow, N - 1);
  const _Float16* b_src0 = Bt + (size_t)bn0 * K + scol;
  const _Float16* b_src1 = Bt + (size_t)bn1 * K + scol;
  _Float16* a_dst0 = &As[wave * 32][0];
  _Float16* a_dst1 = &As[wave * 32 + 16][0];
  _Float16* b_dst0 = &Bs[wave * 32][0];
  _Float16* b_dst1 = &Bs[wave * 32 + 16][0];

  floatx4 acc[4][4] = {};

  for (int k0 = 0; k0 < K; k0 += 32) {
    gld16(a_src0 + k0, a_dst0);
    gld16(a_src1 + k0, a_dst1);
    gld16(b_src0 + k0, b_dst0);
    gld16(b_src1 + k0, b_dst1);
    __syncthreads();

    half8_t af[4], bf[4];
    #pragma unroll
    for (int mi = 0; mi < 4; ++mi)
      af[mi] = *(const half8_t*)&As[wm + mi * 16 + lr][lk];
    #pragma unroll
    for (int ni = 0; ni < 4; ++ni)
      bf[ni] = *(const half8_t*)&Bs[wn + ni * 16 + lr][lk];
    #pragma unroll
    for (int mi = 0; mi < 4; ++mi)
      #pragma unroll
      for (int ni = 0; ni < 4; ++ni)
        acc[mi][ni] = __builtin_amdgcn_mfma_f32_16x16x32_f16(
            af[mi], bf[ni], acc[mi][ni], 0, 0, 0);
    __syncthreads();
  }

  // epilogue: C/D layout col=lane&15, row=(lane>>4)*4+reg
  const int cr = (lane >> 4) * 4;
  #pragma unroll
  for (int mi = 0; mi < 4; ++mi) {
    #pragma unroll
    for (int ni = 0; ni < 4; ++ni) {
      int n = n0 + wn + ni * 16 + lr;
      if (n >= N) continue;
      floatx4 v = acc[mi][ni];
      float bs = bias ? bias[n] : 0.f;
      if (VT && n >= 2 * D) {
        // scatter V third transposed: vt[(b*NH + h)*64 + d][t], t-contiguous x4
        int d  = n - 2 * D;
        int mb = m0 + wm + mi * 16 + cr;
        half4_t h4;
        #pragma unroll
        for (int i = 0; i < 4; ++i) h4[i] = (_Float16)(v[i] + bs);
        *(half4_t*)(vt + ((size_t)((mb >> 10) * NH + (d >> 6)) * 64 + (d & 63)) * T
                       + (mb & 1023)) = h4;
      } else {
        #pragma unroll
        for (int i = 0; i < 4; ++i) {
          int m = m0 + wm + mi * 16 + cr + i;
          float vv = v[i] + bs;
          if (res)  vv += res[(size_t)m * N + n];
          if (GELU) vv = 0.5f * vv * (1.f + erff(vv * 0.70710678118f));
          C[(size_t)m * N + n] = (OutT)vv;
        }
      }
    }
  }
}

// ---------------- launcher ----------------
extern "C" void kernel_launch(void* const* d_in, const int* in_sizes, int n_in,
                              void* d_out, int out_size, void* d_ws, size_t ws_size,
                              hipStream_t stream) {
  const int*   idx   = (const int*)d_in[0];
  const float* wte   = (const float*)d_in[1];
  const float* pos   = (const float*)d_in[2];
  const float* ln1g  = (const float*)d_in[3];
  const float* ln1b  = (const float*)d_in[4];
  const float* qkvw  = (const float*)d_in[5];
  const float* qkvb  = (const float*)d_in[6];
  const float* projw = (const float*)d_in[7];
  const float* projb = (const float*)d_in[8];
  const float* ln2g  = (const float*)d_in[9];
  const float* ln2b  = (const float*)d_in[10];
  const float* fc1w  = (const float*)d_in[11];
  const float* fc1b  = (const float*)d_in[12];
  const float* fc2w  = (const float*)d_in[13];
  const float* fc2b  = (const float*)d_in[14];
  const float* lnfg  = (const float*)d_in[15];
  const float* lnfb  = (const float*)d_in[16];
  float* out = (float*)d_out;

  // ---- workspace layout (fp16 regions 16B-aligned by construction) ----
  float* ws = (float*)d_ws;
  float* x = ws;                                   // [NT, D] f32 residual
  _Float16* big16  = (_Float16*)(x + (size_t)NT * D);  // [NT,4D]: qkv16 [NT,3D] / mlp16 [NT,4D]
  _Float16* vt16   = big16 + (size_t)NT * 4 * D;   // [B*NH*64, T]
  _Float16* hbuf16 = vt16 + (size_t)BATCH * NH * 64 * T;  // [NT, D]
  _Float16* obuf16 = hbuf16 + (size_t)NT * D;      // [NT, D]
  _Float16* q16    = obuf16 + (size_t)NT * D;      // [2304, 768]
  _Float16* p16    = q16  + (size_t)2304 * 768;    // [768, 768]
  _Float16* f116   = p16  + (size_t)768 * 768;     // [3072, 768]
  _Float16* f216   = f116 + (size_t)3072 * 768;    // [768, 3072]
  _Float16* wte16  = f216 + (size_t)768 * 3072;    // [V, D]

  cvt16_kernel<<<2048, 256, 0, stream>>>(wte, wte16, (V * D) / 4);
  embed_kernel<<<NT, 256, 0, stream>>>(idx, wte, pos, x);

  for (int l = 0; l < NL; ++l) {
    wconv_kernel<<<6912, 256, 0, stream>>>(
        qkvw + (size_t)l * D * 3 * D, projw + (size_t)l * D * D,
        fc1w + (size_t)l * D * 4 * D, fc2w + (size_t)l * 4 * D * D,
        q16, p16, f116, f216);
    // ln1 -> fp16
    ln_kernel<<<NT, 256, 0, stream>>>(x, ln1g + (size_t)l * D, ln1b + (size_t)l * D, hbuf16);
    // qkv: Q,K -> big16 [NT,3D]; V -> vt16 transposed
    gemm16_kernel<false, true, _Float16><<<dim3(18, 16), 256, 0, stream>>>(
        hbuf16, q16, qkvb + (size_t)l * 3 * D, nullptr, big16, vt16, NT, 3 * D, D);
    // flash attention -> obuf16
    attn_kernel<<<dim3(T / 64, NH, BATCH), 256, 0, stream>>>(big16, vt16, obuf16);
    // x = x + o @ proj_w + proj_b
    gemm16_kernel<false, false, float><<<dim3(6, 16), 256, 0, stream>>>(
        obuf16, p16, projb + (size_t)l * D, x, x, nullptr, NT, D, D);
    // ln2 -> fp16
    ln_kernel<<<NT, 256, 0, stream>>>(x, ln2g + (size_t)l * D, ln2b + (size_t)l * D, hbuf16);
    // fc1 + GELU -> big16 (fp16 [NT,4D])
    gemm16_kernel<true, false, _Float16><<<dim3(24, 16), 256, 0, stream>>>(
        hbuf16, f116, fc1b + (size_t)l * 4 * D, nullptr, big16, nullptr, NT, 4 * D, D);
    // x = x + gelu @ fc2_w + fc2_b
    gemm16_kernel<false, false, float><<<dim3(6, 16), 256, 0, stream>>>(
        big16, f216, fc2b + (size_t)l * D, x, x, nullptr, NT, D, 4 * D);
  }

  // final LN -> fp16
  ln_kernel<<<NT, 256, 0, stream>>>(x, lnfg, lnfb, hbuf16);
  // logits = h @ wte^T   [NT, V]
  gemm16_kernel<false, false, float><<<dim3((V + 127) / 128, 16), 256, 0, stream>>>(
      hbuf16, wte16, nullptr, nullptr, out, nullptr, NT, V, D);
}

// Round 4
// 3072.072 us; speedup vs baseline: 6.7509x; 1.2212x over previous
//
#include <hip/hip_runtime.h>
#include <math.h>

#define D 768
#define T 1024
#define BATCH 2
#define NH 12
#define NL 12
#define V 50257
#define NT 2048  // BATCH*T

typedef _Float16 half4_t __attribute__((ext_vector_type(4)));
typedef _Float16 half8_t __attribute__((ext_vector_type(8)));
typedef float floatx4 __attribute__((ext_vector_type(4)));

// ---------------- wave helpers ----------------
__device__ inline float wave_reduce_sum(float v) {
  #pragma unroll
  for (int off = 32; off > 0; off >>= 1) v += __shfl_xor(v, off, 64);
  return v;
}

// direct HBM->LDS, 16B per lane (1KB per wave-instruction)
__device__ __forceinline__ void gld16(const _Float16* g, _Float16* l) {
  __builtin_amdgcn_global_load_lds(
      (const __attribute__((address_space(1))) unsigned int*)g,
      (__attribute__((address_space(3))) unsigned int*)l, 16, 0, 0);
}

// ---------------- embedding ----------------
__global__ __launch_bounds__(256) void embed_kernel(const int* __restrict__ idx,
    const float* __restrict__ wte, const float* __restrict__ pos,
    float* __restrict__ x) {
  int row = blockIdx.x;                 // 0..NT-1
  int tok = idx[row];
  int tp  = row & (T - 1);
  const float* ws = wte + (size_t)tok * D;
  const float* ps = pos + (size_t)tp * D;
  float* xr = x + (size_t)row * D;
  for (int i = threadIdx.x; i < D; i += 256) xr[i] = ws[i] + ps[i];
}

// ---------------- fp32 -> fp16 bulk convert (wte) ----------------
__global__ __launch_bounds__(256) void cvt16_kernel(const float* __restrict__ src,
    _Float16* __restrict__ dst, int n4) {
  int i = blockIdx.x * 256 + threadIdx.x;
  int stride = gridDim.x * 256;
  for (; i < n4; i += stride) {
    float4 v = ((const float4*)src)[i];
    half4_t h;
    h[0] = (_Float16)v.x; h[1] = (_Float16)v.y;
    h[2] = (_Float16)v.z; h[3] = (_Float16)v.w;
    ((half4_t*)dst)[i] = h;
  }
}

// ---------------- weight convert+transpose: [K,N]f32 -> [N,K]f16 ----------------
// blockIdx.x: tile id within layer (qkv 1728, proj 576, fc1 2304, fc2 2304 = 6912)
// blockIdx.y: layer offset (0 when converting a single layer)
__global__ __launch_bounds__(256) void wconv_kernel(
    const float* __restrict__ qkvw, const float* __restrict__ projw,
    const float* __restrict__ fc1w, const float* __restrict__ fc2w,
    _Float16* __restrict__ q16, _Float16* __restrict__ p16,
    _Float16* __restrict__ f116, _Float16* __restrict__ f216) {
  int id = blockIdx.x;
  size_t l = blockIdx.y;
  const float* src; _Float16* dst; int K, N, tn;
  if (id < 1728)      { src = qkvw + l * (D * 3 * D); dst = q16  + l * (2304 * 768); K = 768;  N = 2304; tn = id; }
  else if (id < 2304) { src = projw + l * (D * D);    dst = p16  + l * (768 * 768);  K = 768;  N = 768;  tn = id - 1728; }
  else if (id < 4608) { src = fc1w + l * (D * 4 * D); dst = f116 + l * (3072 * 768); K = 768;  N = 3072; tn = id - 2304; }
  else                { src = fc2w + l * (4 * D * D); dst = f216 + l * (3072 * 768); K = 3072; N = 768;  tn = id - 4608; }
  int ntn = N >> 5;
  int tc = (tn % ntn) * 32;   // n0
  int tr = (tn / ntn) * 32;   // k0
  __shared__ float tile[32][33];
  int tx = threadIdx.x & 31, ty = threadIdx.x >> 5;
  #pragma unroll
  for (int j = 0; j < 4; ++j)
    tile[ty + 8 * j][tx] = src[(size_t)(tr + ty + 8 * j) * N + tc + tx];
  __syncthreads();
  #pragma unroll
  for (int j = 0; j < 4; ++j)
    dst[(size_t)(tc + ty + 8 * j) * K + tr + tx] = (_Float16)tile[tx][ty + 8 * j];
}

// ---------------- layernorm: one wave per row, float4 loads, single pass ------
__global__ __launch_bounds__(256) void ln_kernel(const float* __restrict__ x,
    const float* __restrict__ g, const float* __restrict__ bta,
    _Float16* __restrict__ y) {
  const int lane = threadIdx.x & 63, wave = threadIdx.x >> 6;
  const int row = blockIdx.x * 4 + wave;
  const float4* xr = (const float4*)(x + (size_t)row * D);
  half4_t* yr = (half4_t*)(y + (size_t)row * D);

  float4 a[3];
  #pragma unroll
  for (int j = 0; j < 3; ++j) a[j] = xr[lane + 64 * j];

  float s = 0.f;
  #pragma unroll
  for (int j = 0; j < 3; ++j) s += a[j].x + a[j].y + a[j].z + a[j].w;
  float mean = wave_reduce_sum(s) * (1.f / D);

  float v = 0.f;
  #pragma unroll
  for (int j = 0; j < 3; ++j) {
    float dx = a[j].x - mean, dy = a[j].y - mean, dz = a[j].z - mean, dw = a[j].w - mean;
    v += dx * dx + dy * dy + dz * dz + dw * dw;
  }
  float rstd = rsqrtf(wave_reduce_sum(v) * (1.f / D) + 1e-5f);

  #pragma unroll
  for (int j = 0; j < 3; ++j) {
    float4 gg = ((const float4*)g)[lane + 64 * j];
    float4 bb = ((const float4*)bta)[lane + 64 * j];
    half4_t h;
    h[0] = (_Float16)((a[j].x - mean) * rstd * gg.x + bb.x);
    h[1] = (_Float16)((a[j].y - mean) * rstd * gg.y + bb.y);
    h[2] = (_Float16)((a[j].z - mean) * rstd * gg.z + bb.z);
    h[3] = (_Float16)((a[j].w - mean) * rstd * gg.w + bb.w);
    yr[lane + 64 * j] = h;
  }
}

// ---------------- MFMA flash attention (unchanged from round 3) ----------------
__global__ __launch_bounds__(256) void attn_kernel(
    const _Float16* __restrict__ qkv,   // [NT, 3D] fp16 (Q at 0, K at D)
    const _Float16* __restrict__ vt,    // [B*NH*64, T] fp16 (V transposed)
    _Float16* __restrict__ o) {         // [NT, D] fp16
  const int qt   = (int)gridDim.x - 1 - (int)blockIdx.x;
  const int h    = blockIdx.y;
  const int b    = blockIdx.z;
  const int tid  = threadIdx.x;
  const int lane = tid & 63, wave = tid >> 6;
  const int lr = lane & 15, g = lane >> 4;
  const int lk = g * 8;   // frag k-offset (halves)
  const int cr = g * 4;   // C-fragment row base

  __shared__ __align__(16) _Float16 Ks[2][64][32];
  __shared__ __align__(16) _Float16 Vs[2][64][32];
  __shared__ __align__(16) _Float16 Pl[4][16][72];

  const int RS = 3 * D;
  const int q0 = qt * 64 + wave * 16;

  const _Float16* qrow = qkv + (size_t)(b * T + q0 + lr) * RS + h * 64;
  half8_t aq0 = *(const half8_t*)(qrow + lk);
  half8_t aq1 = *(const half8_t*)(qrow + 32 + lk);
  #pragma unroll
  for (int j = 0; j < 8; ++j) { aq0[j] *= (_Float16)0.125f; aq1[j] *= (_Float16)0.125f; }

  const int sr = wave * 16 + (lane >> 2);
  const int sc = (lane & 3) * 8;
  const _Float16* ksrc = qkv + (size_t)(b * T + sr) * RS + D + h * 64 + sc;
  const _Float16* vsrc = vt + (size_t)((b * NH + h) * 64 + sr) * T + sc;
  _Float16* kdst0 = &Ks[0][wave * 16][0];
  _Float16* kdst1 = &Ks[1][wave * 16][0];
  _Float16* vdst0 = &Vs[0][wave * 16][0];
  _Float16* vdst1 = &Vs[1][wave * 16][0];

  floatx4 oa[4] = {};
  float m_r[4] = {-1e30f, -1e30f, -1e30f, -1e30f};
  float l_r[4] = {0.f, 0.f, 0.f, 0.f};

  for (int kt = 0; kt <= qt; ++kt) {
    const _Float16* kp = ksrc + (size_t)(kt * 64) * RS;
    gld16(kp, kdst0);
    gld16(kp + 32, kdst1);
    gld16(vsrc + kt * 64, vdst0);
    gld16(vsrc + kt * 64 + 32, vdst1);
    __syncthreads();

    floatx4 s4[4];
    #pragma unroll
    for (int kc = 0; kc < 4; ++kc) {
      half8_t bk0 = *(const half8_t*)&Ks[0][kc * 16 + lr][lk];
      half8_t bk1 = *(const half8_t*)&Ks[1][kc * 16 + lr][lk];
      floatx4 z = {};
      z = __builtin_amdgcn_mfma_f32_16x16x32_f16(aq0, bk0, z, 0, 0, 0);
      z = __builtin_amdgcn_mfma_f32_16x16x32_f16(aq1, bk1, z, 0, 0, 0);
      s4[kc] = z;
    }
    if (kt == qt) {
      #pragma unroll
      for (int kc = 0; kc < 4; ++kc)
        #pragma unroll
        for (int i = 0; i < 4; ++i)
          if (kc * 16 + lr > wave * 16 + cr + i) s4[kc][i] = -1e30f;
    }

    float alpha[4], psum[4];
    #pragma unroll
    for (int i = 0; i < 4; ++i) {
      float v = fmaxf(fmaxf(s4[0][i], s4[1][i]), fmaxf(s4[2][i], s4[3][i]));
      #pragma unroll
      for (int off = 1; off < 16; off <<= 1) v = fmaxf(v, __shfl_xor(v, off, 64));
      float mn = fmaxf(m_r[i], v);
      alpha[i] = __expf(m_r[i] - mn);
      m_r[i] = mn;
      psum[i] = 0.f;
    }
    #pragma unroll
    for (int kc = 0; kc < 4; ++kc)
      #pragma unroll
      for (int i = 0; i < 4; ++i) {
        float p = __expf(s4[kc][i] - m_r[i]);
        psum[i] += p;
        Pl[wave][cr + i][kc * 16 + lr] = (_Float16)p;
      }
    #pragma unroll
    for (int i = 0; i < 4; ++i) {
      float s = psum[i];
      #pragma unroll
      for (int off = 1; off < 16; off <<= 1) s += __shfl_xor(s, off, 64);
      l_r[i] = l_r[i] * alpha[i] + s;
    }
    #pragma unroll
    for (int dc = 0; dc < 4; ++dc)
      #pragma unroll
      for (int i = 0; i < 4; ++i) oa[dc][i] *= alpha[i];

    half8_t ap0 = *(const half8_t*)&Pl[wave][lr][lk];
    half8_t ap1 = *(const half8_t*)&Pl[wave][lr][32 + lk];
    #pragma unroll
    for (int dc = 0; dc < 4; ++dc) {
      half8_t bv0 = *(const half8_t*)&Vs[0][dc * 16 + lr][lk];
      half8_t bv1 = *(const half8_t*)&Vs[1][dc * 16 + lr][lk];
      oa[dc] = __builtin_amdgcn_mfma_f32_16x16x32_f16(ap0, bv0, oa[dc], 0, 0, 0);
      oa[dc] = __builtin_amdgcn_mfma_f32_16x16x32_f16(ap1, bv1, oa[dc], 0, 0, 0);
    }
    __syncthreads();
  }

  _Float16* orow = o + (size_t)(b * T + q0) * D + h * 64;
  #pragma unroll
  for (int i = 0; i < 4; ++i) {
    float inv = 1.f / l_r[i];
    #pragma unroll
    for (int dc = 0; dc < 4; ++dc)
      orow[(size_t)(cr + i) * D + dc * 16 + lr] = (_Float16)(oa[dc][i] * inv);
  }
}

// ---------------- fp16 MFMA GEMM, m97 structure ----------------
// C[M,N] = A[M,K] @ Bt[N,K]^T (+bias,+res,+GELU). A,Bt fp16 K-contiguous.
// Block->tile mapping: dispatch-order flat id, 8-XCD chunked, decoded n-major
// so each XCD owns a contiguous n-panel range (weight panel fetched once).
// ATOMIC: split-K over gridDim.z; partials atomicAdd'ed into C (C pre-holds
// residual); bias added by z==0 blocks only.
// VT: for n>=2D (V third of qkv), write transposed into vt[B*NH*64][T].
template <bool GELU, bool VT, bool ATOMIC, typename OutT>
__global__ __launch_bounds__(256) void gemm16_kernel(
    const _Float16* __restrict__ A, const _Float16* __restrict__ Bt,
    const float* __restrict__ bias, const float* __restrict__ res,
    OutT* __restrict__ C, _Float16* __restrict__ vt, int M, int N, int K) {
  __shared__ __align__(16) _Float16 As[128][32];
  __shared__ __align__(16) _Float16 Bs[128][32];
  const int t = threadIdx.x;
  const int lane = t & 63, wave = t >> 6;

  // n-major XCD-chunked tile mapping (nwg % 8 == 0 in all launches)
  const int gx = gridDim.x, gy = gridDim.y;
  const int nwg = gx * gy;
  int f = blockIdx.y * gx + blockIdx.x;         // HW dispatch order (x fastest)
  int id = (f & 7) * (nwg >> 3) + (f >> 3);     // XCD gets contiguous chunk
  const int n0 = (id / gy) * 128;               // n-major within chunk
  const int m0 = (id % gy) * 128;

  // split-K range
  const int ks = K / gridDim.z;
  const int kbeg = blockIdx.z * ks, kend = kbeg + ks;

  const int wm = (wave >> 1) * 64, wn = (wave & 1) * 64;
  const int lr = lane & 15;            // frag row (A) / col (B)
  const int lk = (lane >> 4) * 8;      // frag k-offset (halves)

  const int srow = lane >> 2;          // 0..15
  const int scol = (lane & 3) * 8;     // halves
  const _Float16* a_src0 = A + (size_t)(m0 + wave * 32 + srow) * K + scol;
  const _Float16* a_src1 = a_src0 + (size_t)16 * K;
  const int bn0 = min(n0 + wave * 32 + srow, N - 1);       // clamp (logits tail)
  const int bn1 = min(n0 + wave * 32 + 16 + srow, N - 1);
  const _Float16* b_src0 = Bt + (size_t)bn0 * K + scol;
  const _Float16* b_src1 = Bt + (size_t)bn1 * K + scol;
  _Float16* a_dst0 = &As[wave * 32][0];
  _Float16* a_dst1 = &As[wave * 32 + 16][0];
  _Float16* b_dst0 = &Bs[wave * 32][0];
  _Float16* b_dst1 = &Bs[wave * 32 + 16][0];

  floatx4 acc[4][4] = {};

  for (int k0 = kbeg; k0 < kend; k0 += 32) {
    gld16(a_src0 + k0, a_dst0);
    gld16(a_src1 + k0, a_dst1);
    gld16(b_src0 + k0, b_dst0);
    gld16(b_src1 + k0, b_dst1);
    __syncthreads();

    half8_t af[4], bf[4];
    #pragma unroll
    for (int mi = 0; mi < 4; ++mi)
      af[mi] = *(const half8_t*)&As[wm + mi * 16 + lr][lk];
    #pragma unroll
    for (int ni = 0; ni < 4; ++ni)
      bf[ni] = *(const half8_t*)&Bs[wn + ni * 16 + lr][lk];
    #pragma unroll
    for (int mi = 0; mi < 4; ++mi)
      #pragma unroll
      for (int ni = 0; ni < 4; ++ni)
        acc[mi][ni] = __builtin_amdgcn_mfma_f32_16x16x32_f16(
            af[mi], bf[ni], acc[mi][ni], 0, 0, 0);
    __syncthreads();
  }

  // epilogue: C/D layout col=lane&15, row=(lane>>4)*4+reg
  const int cr = (lane >> 4) * 4;
  #pragma unroll
  for (int mi = 0; mi < 4; ++mi) {
    #pragma unroll
    for (int ni = 0; ni < 4; ++ni) {
      int n = n0 + wn + ni * 16 + lr;
      if (n >= N) continue;
      floatx4 v = acc[mi][ni];
      float bs = (bias && (!ATOMIC || blockIdx.z == 0)) ? bias[n] : 0.f;
      if (VT && n >= 2 * D) {
        int d  = n - 2 * D;
        int mb = m0 + wm + mi * 16 + cr;
        half4_t h4;
        #pragma unroll
        for (int i = 0; i < 4; ++i) h4[i] = (_Float16)(v[i] + bs);
        *(half4_t*)(vt + ((size_t)((mb >> 10) * NH + (d >> 6)) * 64 + (d & 63)) * T
                       + (mb & 1023)) = h4;
      } else if (ATOMIC) {
        #pragma unroll
        for (int i = 0; i < 4; ++i) {
          int m = m0 + wm + mi * 16 + cr + i;
          atomicAdd((float*)&C[(size_t)m * N + n], v[i] + bs);
        }
      } else {
        #pragma unroll
        for (int i = 0; i < 4; ++i) {
          int m = m0 + wm + mi * 16 + cr + i;
          float vv = v[i] + bs;
          if (res)  vv += res[(size_t)m * N + n];
          if (GELU) vv = 0.5f * vv * (1.f + erff(vv * 0.70710678118f));
          C[(size_t)m * N + n] = (OutT)vv;
        }
      }
    }
  }
}

// ---------------- launcher ----------------
extern "C" void kernel_launch(void* const* d_in, const int* in_sizes, int n_in,
                              void* d_out, int out_size, void* d_ws, size_t ws_size,
                              hipStream_t stream) {
  const int*   idx   = (const int*)d_in[0];
  const float* wte   = (const float*)d_in[1];
  const float* pos   = (const float*)d_in[2];
  const float* ln1g  = (const float*)d_in[3];
  const float* ln1b  = (const float*)d_in[4];
  const float* qkvw  = (const float*)d_in[5];
  const float* qkvb  = (const float*)d_in[6];
  const float* projw = (const float*)d_in[7];
  const float* projb = (const float*)d_in[8];
  const float* ln2g  = (const float*)d_in[9];
  const float* ln2b  = (const float*)d_in[10];
  const float* fc1w  = (const float*)d_in[11];
  const float* fc1b  = (const float*)d_in[12];
  const float* fc2w  = (const float*)d_in[13];
  const float* fc2b  = (const float*)d_in[14];
  const float* lnfg  = (const float*)d_in[15];
  const float* lnfb  = (const float*)d_in[16];
  float* out = (float*)d_out;

  // ---- workspace layout ----
  float* ws = (float*)d_ws;
  float* x = ws;                                        // [NT, D] f32 residual
  _Float16* big16  = (_Float16*)(x + (size_t)NT * D);   // [NT,4D]
  _Float16* vt16   = big16 + (size_t)NT * 4 * D;        // [B*NH*64, T]
  _Float16* hbuf16 = vt16 + (size_t)BATCH * NH * 64 * T;// [NT, D]
  _Float16* obuf16 = hbuf16 + (size_t)NT * D;           // [NT, D]
  _Float16* wte16  = obuf16 + (size_t)NT * D;           // [V, D]
  _Float16* wbase  = wte16 + (size_t)V * D;             // weights (1 or 12 layers)

  const size_t QSZ = (size_t)2304 * 768, PSZ = (size_t)768 * 768;
  const size_t F1SZ = (size_t)3072 * 768, F2SZ = (size_t)3072 * 768;
  const size_t PERL = QSZ + PSZ + F1SZ + F2SZ;          // 7,077,888 halves
  const size_t fixed_bytes = (char*)wbase - (char*)d_ws;
  const bool all12 = ws_size >= fixed_bytes + 12 * PERL * sizeof(_Float16);
  const int nlw = all12 ? 12 : 1;

  _Float16* q16  = wbase;
  _Float16* p16  = q16  + QSZ * nlw;
  _Float16* f116 = p16  + PSZ * nlw;
  _Float16* f216 = f116 + F1SZ * nlw;

  cvt16_kernel<<<2048, 256, 0, stream>>>(wte, wte16, (V * D) / 4);
  embed_kernel<<<NT, 256, 0, stream>>>(idx, wte, pos, x);
  if (all12)
    wconv_kernel<<<dim3(6912, 12), 256, 0, stream>>>(
        qkvw, projw, fc1w, fc2w, q16, p16, f116, f216);

  for (int l = 0; l < NL; ++l) {
    size_t lw = all12 ? (size_t)l : 0;
    if (!all12)
      wconv_kernel<<<dim3(6912, 1), 256, 0, stream>>>(
          qkvw + (size_t)l * D * 3 * D, projw + (size_t)l * D * D,
          fc1w + (size_t)l * D * 4 * D, fc2w + (size_t)l * 4 * D * D,
          q16, p16, f116, f216);
    // ln1 -> fp16
    ln_kernel<<<NT / 4, 256, 0, stream>>>(x, ln1g + (size_t)l * D, ln1b + (size_t)l * D, hbuf16);
    // qkv: Q,K -> big16 [NT,3D]; V -> vt16 transposed
    gemm16_kernel<false, true, false, _Float16><<<dim3(18, 16), 256, 0, stream>>>(
        hbuf16, q16 + lw * QSZ, qkvb + (size_t)l * 3 * D, nullptr, big16, vt16, NT, 3 * D, D);
    // flash attention -> obuf16
    attn_kernel<<<dim3(T / 64, NH, BATCH), 256, 0, stream>>>(big16, vt16, obuf16);
    // x += o @ proj_w + proj_b  (split-K=2, atomic into residual)
    gemm16_kernel<false, false, true, float><<<dim3(6, 16, 2), 256, 0, stream>>>(
        obuf16, p16 + lw * PSZ, projb + (size_t)l * D, nullptr, x, nullptr, NT, D, D);
    // ln2 -> fp16
    ln_kernel<<<NT / 4, 256, 0, stream>>>(x, ln2g + (size_t)l * D, ln2b + (size_t)l * D, hbuf16);
    // fc1 + GELU -> big16 (fp16 [NT,4D])
    gemm16_kernel<true, false, false, _Float16><<<dim3(24, 16), 256, 0, stream>>>(
        hbuf16, f116 + lw * F1SZ, fc1b + (size_t)l * 4 * D, nullptr, big16, nullptr, NT, 4 * D, D);
    // x += gelu @ fc2_w + fc2_b  (split-K=4, atomic into residual)
    gemm16_kernel<false, false, true, float><<<dim3(6, 16, 4), 256, 0, stream>>>(
        big16, f216 + lw * F2SZ, fc2b + (size_t)l * D, nullptr, x, nullptr, NT, D, 4 * D);
  }

  // final LN -> fp16
  ln_kernel<<<NT / 4, 256, 0, stream>>>(x, lnfg, lnfb, hbuf16);
  // logits = h @ wte^T   [NT, V]
  gemm16_kernel<false, false, false, float><<<dim3((V + 127) / 128, 16), 256, 0, stream>>>(
      hbuf16, wte16, nullptr, nullptr, out, nullptr, NT, V, D);
}